// Round 5
// baseline (44.353 us; speedup 1.0000x reference)
//
#include <hip/hip_runtime.h>

#define INP (128*128*64)   // 1048576
#define NB 8
#define NBLK1 4096         // spatial blocks: INP / 256

typedef __attribute__((ext_vector_type(4))) float f32x4;
typedef int v4i __attribute__((ext_vector_type(4)));

// ---------------------------------------------------------------------------
// Buffer-resource loads: 32-bit voffset addressing (pure VALU saving).
// All offsets are clamped in-bounds by construction — no reliance on the
// hardware OOB path (that gamble failed in R3 at the negative-offset edge).
// ---------------------------------------------------------------------------
#if __has_builtin(__builtin_amdgcn_make_buffer_rsrc) && __has_builtin(__builtin_amdgcn_raw_buffer_load_b32)
#define RSRC_T __amdgpu_buffer_rsrc_t
__device__ __forceinline__ RSRC_T make_rsrc(const float* p) {
    return __builtin_amdgcn_make_buffer_rsrc((void*)p, (short)0, INP * 4, 0x00020000);
}
__device__ __forceinline__ float bload(RSRC_T r, int boff) {
    return __builtin_bit_cast(float, __builtin_amdgcn_raw_buffer_load_b32(r, boff, 0, 0));
}
#else
#define RSRC_T v4i
__device__ __forceinline__ RSRC_T make_rsrc(const float* p) {
    union { const float* p; unsigned u[2]; } pun; pun.p = p;
    RSRC_T r;
    r.x = (int)pun.u[0]; r.y = (int)pun.u[1]; r.z = INP * 4; r.w = 0x00020000;
    return r;
}
__device__ __forceinline__ float bload(RSRC_T r, int boff) {
    return __builtin_amdgcn_raw_buffer_load_f32(r, boff, 0, 0);
}
#endif

// ---------------------------------------------------------------------------
// K1: one thread = one (batch, voxel) trilinear sample. TLP (131K waves)
// hides gather latency instead of the ILP the compiler keeps serializing.
// blockIdx.y = batch -> theta/r_index access is wave-uniform (scalar loads).
// Also accumulates per-(batch, spatial-block) dot partials.
// ---------------------------------------------------------------------------
__global__ __launch_bounds__(256) void k_sample(
    const float* __restrict__ x,       // (8, INP) as (8,128,128,64) z,y,x
    const int*   __restrict__ r_index, // (8,)
    const float* __restrict__ theta,   // (100,3,4)
    const float* __restrict__ lnw,     // (INP)
    float* __restrict__ x_reg,         // out[0 .. 8*INP)
    float* __restrict__ partial)       // ws: (8, NBLK1)
{
    const int b = blockIdx.y;
    const int i = blockIdx.x * 256 + threadIdx.x;   // spatial flat idx
    const int w = i & 63;
    const int h = (i >> 6) & 127;
    const int d = i >> 13;

    // normalized coords, align_corners=False: (2k+1)/n - 1
    const float xs = fmaf((float)w, 1.f/32.f, 1.f/64.f  - 1.f);
    const float ys = fmaf((float)h, 1.f/64.f, 1.f/128.f - 1.f);
    const float zs = fmaf((float)d, 1.f/64.f, 1.f/128.f - 1.f);

    const float* __restrict__ t = theta + r_index[b] * 12;   // uniform
    float ix = fmaf(t[0], xs, fmaf(t[1], ys, fmaf(t[2],  zs, t[3])));
    float iy = fmaf(t[4], xs, fmaf(t[5], ys, fmaf(t[6],  zs, t[7])));
    float iz = fmaf(t[8], xs, fmaf(t[9], ys, fmaf(t[10], zs, t[11])));
    ix = fmaf(ix, 32.f, 31.5f);
    iy = fmaf(iy, 64.f, 63.5f);
    iz = fmaf(iz, 64.f, 63.5f);

    const float fx = floorf(ix), fy = floorf(iy), fz = floorf(iz);
    const int x0 = (int)fx, y0 = (int)fy, z0 = (int)fz;
    const int x1 = x0 + 1,  y1 = y0 + 1,  z1 = z0 + 1;

    float wx1 = ix - fx, wx0 = 1.f - wx1;
    float wy1 = iy - fy, wy0 = 1.f - wy1;
    float wz1 = iz - fz, wz0 = 1.f - wz1;
    // zeros-padding: zero the axis weight of any out-of-range plane
    wx0 = ((unsigned)x0 < 64u)  ? wx0 : 0.f;
    wx1 = ((unsigned)x1 < 64u)  ? wx1 : 0.f;
    wy0 = ((unsigned)y0 < 128u) ? wy0 : 0.f;
    wy1 = ((unsigned)y1 < 128u) ? wy1 : 0.f;
    wz0 = ((unsigned)z0 < 128u) ? wz0 : 0.f;
    wz1 = ((unsigned)z1 < 128u) ? wz1 : 0.f;

    // clamped, always-in-bounds byte offsets
    const int xc0 = min(max(x0, 0), 63),  xc1 = min(max(x1, 0), 63);
    const int yc0 = min(max(y0, 0), 127), yc1 = min(max(y1, 0), 127);
    const int zc0 = min(max(z0, 0), 127), zc1 = min(max(z1, 0), 127);
    const int rb00 = ((zc0 << 7) + yc0) << 8;   // byte row bases
    const int rb01 = ((zc0 << 7) + yc1) << 8;
    const int rb10 = ((zc1 << 7) + yc0) << 8;
    const int rb11 = ((zc1 << 7) + yc1) << 8;
    const int xb0 = xc0 << 2, xb1 = xc1 << 2;

    const RSRC_T r = make_rsrc(x + (size_t)b * INP);
    const float v000 = bload(r, rb00 + xb0);
    const float v001 = bload(r, rb00 + xb1);
    const float v010 = bload(r, rb01 + xb0);
    const float v011 = bload(r, rb01 + xb1);
    const float v100 = bload(r, rb10 + xb0);
    const float v101 = bload(r, rb10 + xb1);
    const float v110 = bload(r, rb11 + xb0);
    const float v111 = bload(r, rb11 + xb1);

    const float bx00 = fmaf(wx1, v001, wx0 * v000);
    const float bx01 = fmaf(wx1, v011, wx0 * v010);
    const float bx10 = fmaf(wx1, v101, wx0 * v100);
    const float bx11 = fmaf(wx1, v111, wx0 * v110);
    const float by0  = fmaf(wy1, bx01, wy0 * bx00);
    const float by1  = fmaf(wy1, bx11, wy0 * bx10);
    const float out  = fmaf(wz1, by1, wz0 * by0);

    __builtin_nontemporal_store(out, x_reg + (size_t)b * INP + i);

    // deterministic block reduction of out * lnw[i] for this batch
    float acc = out * lnw[i];
    __shared__ float sm[4];
    const int lane = threadIdx.x & 63;
    const int wv   = threadIdx.x >> 6;
    #pragma unroll
    for (int off = 32; off > 0; off >>= 1) acc += __shfl_down(acc, off, 64);
    if (lane == 0) sm[wv] = acc;
    __syncthreads();
    if (threadIdx.x == 0)
        partial[b * NBLK1 + blockIdx.x] = sm[0] + sm[1] + sm[2] + sm[3];
}

// ---------------------------------------------------------------------------
// K2: reduce (8, NBLK1) partials -> s[8]
// ---------------------------------------------------------------------------
__global__ __launch_bounds__(256) void k_reduce(
    const float* __restrict__ partial, float* __restrict__ s)
{
    const int b = blockIdx.x;
    float v = 0.f;
    for (int t = threadIdx.x; t < NBLK1; t += 256) v += partial[b * NBLK1 + t];
    __shared__ float sm[4];
    const int lane = threadIdx.x & 63;
    const int wv   = threadIdx.x >> 6;
    #pragma unroll
    for (int off = 32; off > 0; off >>= 1) v += __shfl_down(v, off, 64);
    if (lane == 0) sm[wv] = v;
    __syncthreads();
    if (threadIdx.x == 0) s[b] = sm[0] + sm[1] + sm[2] + sm[3];
}

// ---------------------------------------------------------------------------
// K3: L[b,i] = s[b] * lnw[i], float4 vectorized, nontemporal stores
// ---------------------------------------------------------------------------
__global__ __launch_bounds__(256) void k_outer(
    const float* __restrict__ lnw, const float* __restrict__ s,
    float* __restrict__ L)
{
    const int i = blockIdx.x * 256 + threadIdx.x;   // over INP/4
    const f32x4 w4 = ((const f32x4*)lnw)[i];
    #pragma unroll
    for (int b = 0; b < NB; ++b) {
        const float sb = s[b];
        f32x4 o = sb * w4;
        __builtin_nontemporal_store(o, (f32x4*)(L + (size_t)b * INP) + i);
    }
}

extern "C" void kernel_launch(void* const* d_in, const int* in_sizes, int n_in,
                              void* d_out, int out_size, void* d_ws, size_t ws_size,
                              hipStream_t stream) {
    const float* x       = (const float*)d_in[0];
    const int*   r_index = (const int*)d_in[1];
    const float* theta   = (const float*)d_in[2];
    const float* lnw     = (const float*)d_in[3];

    float* x_reg = (float*)d_out;                       // (8, INP)
    float* L     = (float*)d_out + (size_t)NB * INP;    // (8, INP)

    float* partial = (float*)d_ws;          // 8*4096 floats = 128 KB
    float* s       = partial + NB * NBLK1;  // 8 floats

    dim3 grid1(NBLK1, NB);
    k_sample<<<grid1, 256, 0, stream>>>(x, r_index, theta, lnw, x_reg, partial);
    k_reduce<<<NB, 256, 0, stream>>>(partial, s);
    k_outer<<<INP / 4 / 256, 256, 0, stream>>>(lnw, s, L);
}